// Round 10
// baseline (610.349 us; speedup 1.0000x reference)
//
#include <hip/hip_runtime.h>
#include <hip/hip_bf16.h>
#include <stdint.h>

typedef _Float16 f16;
typedef _Float16 f16x8 __attribute__((ext_vector_type(8)));
typedef _Float16 f16x4 __attribute__((ext_vector_type(4)));
typedef float    f32x4 __attribute__((ext_vector_type(4)));

#define B_N 1024
#define T_N 128
#define U_N 256
#define G3  768    // 3U
#define NC  1024   // pre columns, permuted: col' = u*4 + part, part in {r,z,xh,eh}
#define KC  512    // concat K: [inputs | em_sum]
#define M_N (B_N * T_N)
#define S16P 264   // f16 LDS row stride

__device__ __forceinline__ void glds16(const void* g, void* l) {
  __builtin_amdgcn_global_load_lds((const __attribute__((address_space(1))) unsigned int*)g,
                                   (__attribute__((address_space(3))) unsigned int*)l, 16, 0, 0);
}

// ---------------- prep: B2 (f16, tile-major pre-swizzled), bias' (f32 1024), UhF ----------------
// UhF for 4-wave scan: frag f = (w*8 + kk)*12 + nt ; element = f*512 + lane*8 + j
__global__ void k_prep(const float* __restrict__ Wx, const float* __restrict__ Uh,
                       const float* __restrict__ Ve, const float* __restrict__ bsrc,
                       f16* __restrict__ B2, float* __restrict__ bias, f16* __restrict__ UhF)
{
  int idx = blockIdx.x * 256 + threadIdx.x;
  if (idx < NC * KC) {
    int e = idx & 7, slot = (idx >> 3) & 3, r = (idx >> 5) & 127;
    int kt = (idx >> 12) & 15, nt8 = idx >> 16;
    int swz = ((r >> 2) ^ r) & 3;
    int np = nt8 * 128 + r;
    int k  = kt * 32 + ((slot ^ swz) & 3) * 8 + e;
    int u = np >> 2, part = np & 3;
    float v;
    if (part == 0)      v = (k < 256) ? Wx[k * G3 + u]         : Ve[(k - 256) * G3 + u];
    else if (part == 1) v = (k < 256) ? Wx[k * G3 + 256 + u]   : Ve[(k - 256) * G3 + 256 + u];
    else if (part == 2) v = (k < 256) ? Wx[k * G3 + 512 + u]   : 0.f;
    else                v = (k < 256) ? 0.f                    : Ve[(k - 256) * G3 + 512 + u];
    B2[idx] = (f16)v;
    return;
  }
  int i2 = idx - NC * KC;
  if (i2 < U_N * G3) {
    int j = i2 & 7, lane = (i2 >> 3) & 63, fn = i2 >> 9;   // fn in [0,384)
    int nt = fn % 12, kkw = fn / 12;
    int kk = kkw & 7, w = kkw >> 3;                        // w in [0,4)
    int k = kk * 32 + (lane >> 4) * 8 + j;
    int npp = w * 192 + nt * 16 + (lane & 15);
    int q = npp >> 4;
    int u = (q / 3) * 16 + (npp & 15), gate = q % 3;
    UhF[i2] = (f16)Uh[k * G3 + gate * 256 + u];
    return;
  }
  int i3 = i2 - U_N * G3;
  if (i3 < NC) {
    int u = i3 >> 2, part = i3 & 3;
    bias[i3] = (part < 3) ? bsrc[part * 256 + u] : 0.f;
  }
}

// ---------------- build A2 (f16, tile-major pre-swizzled) ----------------
__global__ __launch_bounds__(256) void k_build_a2(const float* __restrict__ inp, const int* __restrict__ et,
                           const int* __restrict__ cmk, const float* __restrict__ emb,
                           f16* __restrict__ A2)
{
  int idx = blockIdx.x * 256 + threadIdx.x;        // 8,388,608 total
  int slot = idx & 3, t = (idx >> 2) & 127, kt = (idx >> 9) & 15, b = idx >> 13;
  int swz = ((t >> 2) ^ t) & 3;
  int k0 = kt * 32 + ((slot ^ swz) & 3) * 8;
  int m = b * 128 + t;
  f16x8 v;
  if (k0 < 256) {
    const float* s = inp + (size_t)m * 256 + k0;
    #pragma unroll
    for (int j = 0; j < 8; ++j) v[j] = (f16)s[j];
  } else {
    int c = k0 - 256;
    const int* e  = et  + (size_t)m * 4;
    const int* cm = cmk + (size_t)m * 4;
    float a[8] = {0,0,0,0,0,0,0,0};
    #pragma unroll
    for (int r = 0; r < 4; ++r)
      if (cm[r]) {
        const float* es = emb + e[r] * U_N + c;
        #pragma unroll
        for (int j = 0; j < 8; ++j) a[j] += es[j];
      }
    #pragma unroll
    for (int j = 0; j < 8; ++j) v[j] = (f16)a[j];
  }
  *(f16x8*)(A2 + (size_t)idx * 8) = v;
}

// ---------------- GEMM: pre[M][1024] (f16) = A[M][512] @ B^T + bias' (unchanged, proven) ----------------
__global__ __launch_bounds__(256) void k_gemm2(const f16* __restrict__ A2,
                                               const f16* __restrict__ B2,
                                               const float* __restrict__ bias,
                                               f16* __restrict__ C)
{
  __shared__ __align__(16) f16 sbuf[3][2][4096];   // 49152 B
  const int tid  = threadIdx.x;
  const int lane = tid & 63, wv = tid >> 6;
  const int wm = wv >> 1, wn = wv & 1;
  const int l15 = lane & 15, lhi = lane >> 4;
  const int wg = (blockIdx.x & 7) * 1024 + (blockIdx.x >> 3);
  const int mt = wg >> 3, nt = wg & 7;
  const int m0 = mt * 128, n0 = nt * 128;

  const f16* gabase = A2 + (size_t)mt * 16 * 4096 + wv * 1024 + lane * 8;
  const f16* gbbase = B2 + (size_t)nt * 16 * 4096 + wv * 1024 + lane * 8;

  #define STAGE(kt_, buf_) do {                                             \
    int kk_ = (kt_);                                                        \
    glds16(gabase + (size_t)kk_ * 4096,       &sbuf[buf_][0][wv * 1024]);   \
    glds16(gabase + (size_t)kk_ * 4096 + 512, &sbuf[buf_][0][wv * 1024 + 512]); \
    glds16(gbbase + (size_t)kk_ * 4096,       &sbuf[buf_][1][wv * 1024]);   \
    glds16(gbbase + (size_t)kk_ * 4096 + 512, &sbuf[buf_][1][wv * 1024 + 512]); \
  } while (0)

  f32x4 acc[4][4] = {};

  STAGE(0, 0);
  STAGE(1, 1);
  __builtin_amdgcn_sched_barrier(0);

  int aoff[4], boff[4];
  #pragma unroll
  for (int i = 0; i < 4; ++i) {
    int ar = wm * 64 + i * 16 + l15;
    aoff[i] = ar * 32 + ((lhi ^ ((ar >> 2) ^ ar)) & 3) * 8;
    int br = wn * 64 + i * 16 + l15;
    boff[i] = br * 32 + ((lhi ^ ((br >> 2) ^ br)) & 3) * 8;
  }

  for (int t = 0; t < 16; ++t) {
    const int buf  = t % 3;
    const int bufp = (t + 2) % 3;
    STAGE((t + 2 < 16) ? (t + 2) : 15, bufp);
    __builtin_amdgcn_sched_barrier(0);
    asm volatile("s_waitcnt vmcnt(8)" ::: "memory");
    __builtin_amdgcn_sched_barrier(0);
    __builtin_amdgcn_s_barrier();
    __builtin_amdgcn_sched_barrier(0);

    const f16* sA = &sbuf[buf][0][0];
    const f16* sB = &sbuf[buf][1][0];
    f16x8 af[4], bf[4];
    #pragma unroll
    for (int i = 0; i < 4; ++i) {
      af[i] = *(const f16x8*)(sA + aoff[i]);
      bf[i] = *(const f16x8*)(sB + boff[i]);
    }
    __builtin_amdgcn_s_setprio(1);
    #pragma unroll
    for (int i = 0; i < 4; ++i)
      #pragma unroll
      for (int j = 0; j < 4; ++j)
        acc[i][j] = __builtin_amdgcn_mfma_f32_16x16x32_f16(af[i], bf[j], acc[i][j], 0, 0, 0);
    __builtin_amdgcn_s_setprio(0);

    asm volatile("s_waitcnt lgkmcnt(0)" ::: "memory");
    __builtin_amdgcn_s_barrier();
    __builtin_amdgcn_sched_barrier(0);
  }

  float bv[4];
  #pragma unroll
  for (int j = 0; j < 4; ++j) bv[j] = bias[n0 + wn * 64 + j * 16 + l15];
  asm volatile("s_waitcnt vmcnt(0)" ::: "memory");
  __builtin_amdgcn_sched_barrier(0);
  __builtin_amdgcn_s_barrier();

  f16* ep = &sbuf[0][0][0];
  #pragma unroll
  for (int i = 0; i < 4; ++i)
    #pragma unroll
    for (int j = 0; j < 4; ++j)
      #pragma unroll
      for (int r = 0; r < 4; ++r)
        ep[(wm * 64 + i * 16 + lhi * 4 + r) * 132 + wn * 64 + j * 16 + l15] =
            (f16)(acc[i][j][r] + bv[j]);
  __syncthreads();

  #pragma unroll
  for (int it = 0; it < 8; ++it) {
    int row = it * 16 + (tid >> 4), chunk = tid & 15;
    *(f16x8*)(C + (size_t)(m0 + row) * 1024 + n0 + chunk * 8) =
        *(const f16x8*)(ep + row * 132 + chunk * 8);
  }
  #undef STAGE
}

// ---------------- scan: 256 blocks x 256 threads (4 waves, 1 wave/SIMD), 4 batch rows ----------------
// Wave w owns Uh cols [192w,192w+192): 96 B-frags (~384 regs) + 12 acc; 512-reg budget at 1 wave/EU.
// Builtin MFMA (compiler handles AGPR allocation + all hazards).
// Ledger: 4 VMEM ops/wave/step: {2 dep-glds (w<3) | 2 h-stores (w==3)} + 2 pre-glds(t+2).
// One vmcnt(2) per step (phase A): retires dep(t), pre(t), and h-stores of step t-1.
__global__ __launch_bounds__(256, 1) void k_scan7(
    const f16* __restrict__ pre,   // [B*T][1024], col' = u*4 + {r,z,xh,eh}
    const f16* __restrict__ UhF,
    const int* __restrict__ dep,   // [B][T][3]
    const int* __restrict__ cmk,   // [B][T][4]
    const int* __restrict__ msk,   // [B][T]
    f16* __restrict__ H16,         // [T+1][B][256] f16 (row T = scratch)
    float* __restrict__ out)       // [B][256]
{
  __shared__ __align__(16) f16 s16[16 * S16P];     // 8448 B
  __shared__ __align__(16) f16 hring[2][1024];     // 4096 B
  __shared__ __align__(16) f16 dbuf[2][3072];      // 12288 B
  __shared__ __align__(16) f16 spre[3][4096];      // 24576 B
  __shared__ int sidx_all[4][T_N][8];              // 16384 B

  const int tid  = threadIdx.x;
  const int lane = tid & 63, w = tid >> 6;
  const int l15  = lane & 15, lhi = lane >> 4;
  const int b0   = blockIdx.x * 4;

  // Uh fragments -> registers (whole kernel; compiler assigns AGPRs under pressure)
  f16x8 uh[96];
  {
    const f16* ub = UhF + (size_t)w * 49152 + lane * 8;
    #pragma unroll
    for (int i = 0; i < 96; ++i) uh[i] = *(const f16x8*)(ub + i * 512);
  }

  // zero hring + s16
  for (int i = tid; i < 1024; i += 256) ((int*)hring)[i] = 0;
  for (int i = tid; i < 2112; i += 256) ((int*)s16)[i] = 0;

  // preload ALL sidx: [4 rows][128 t][8 fields]
  for (int i = tid; i < 4 * T_N * 8; i += 256) {
    int rr = i >> 10, rem = i & 1023, tt = rem >> 3, f = rem & 7;
    size_t b = b0 + rr;
    int v;
    if (f < 4)      v = cmk[(b * T_N + tt) * 4 + f];
    else if (f < 7) v = dep[(b * T_N + tt) * 3 + (f - 4)];
    else            v = msk[b * T_N + tt];
    sidx_all[rr][tt][f] = v;
  }
  __syncthreads();    // full drain — ledger starts clean
  __builtin_amdgcn_sched_barrier(0);

  // per-thread invariant bases
  const f16* spre_src = pre + ((size_t)(b0 + w) * T_N) * 1024 + lane * 8;  // row b0+w
  const int  sprd = w * 1024;
  const int q0 = 4 * w + (lane >> 5), q1 = q0 + 2;       // (row,dep) pair ids (w<3: 0..11)
  const int r0 = q0 / 3, dm0 = q0 - r0 * 3;
  const int r1 = q1 / 3, dm1 = q1 - r1 * 3;
  const f16* dsrc0 = H16 + (size_t)(b0 + (r0 & 3)) * 256 + (lane & 31) * 8;
  const f16* dsrc1 = H16 + (size_t)(b0 + (r1 & 3)) * 256 + (lane & 31) * 8;
  const int srow0 = (lane >> 5), srow1 = 2 + (lane >> 5);  // wave 3 store rows
  const int soff  = (lane & 31) * 8;

  // prologue: pre rows 0,1 (4 ops/wave)
  glds16(spre_src,        &spre[0][sprd]);
  glds16(spre_src + 512,  &spre[0][sprd + 512]);
  glds16(spre_src + 1024, &spre[1][sprd]);
  glds16(spre_src + 1536, &spre[1][sprd + 512]);
  __builtin_amdgcn_sched_barrier(0);

  for (int t = 0; t < T_N; ++t) {
    // ---- phase A ----
    asm volatile("s_waitcnt vmcnt(2)" ::: "memory");
    __builtin_amdgcn_sched_barrier(0);

    if (tid < 128) {
      const int rr = tid >> 5, uo = (tid & 31) * 8;
      const int* six = &sidx_all[rr][t][0];
      int cm0 = six[0];
      int cma[3] = {six[1], six[2], six[3]};
      int dda[3] = {six[4], six[5], six[6]};
      f16x8 hprev = *(const f16x8*)&hring[(t + 1) & 1][rr * 256 + uo];  // h[t-1]
      f16x8 hold  = *(const f16x8*)&hring[t & 1][rr * 256 + uo];        // h[t-2]
      f32x4 a0 = {0.f,0.f,0.f,0.f}, a1 = {0.f,0.f,0.f,0.f};
      if (cm0) {
        #pragma unroll
        for (int j = 0; j < 4; ++j) { a0[j] += (float)hprev[j]; a1[j] += (float)hprev[j + 4]; }
      }
      #pragma unroll
      for (int r = 0; r < 3; ++r) {
        f16x8 dv = *(const f16x8*)&dbuf[t & 1][(rr * 3 + r) * 256 + uo];
        int d = dda[r];
        f16x8 src = (d == t - 1) ? hprev : ((d == t - 2) ? hold : dv);
        if (cma[r] && (d < t)) {
          #pragma unroll
          for (int j = 0; j < 4; ++j) { a0[j] += (float)src[j]; a1[j] += (float)src[j + 4]; }
        }
      }
      f16x8 s8;
      #pragma unroll
      for (int j = 0; j < 4; ++j) { s8[j] = (f16)a0[j]; s8[j + 4] = (f16)a1[j]; }
      *(f16x8*)&s16[(rr * 4) * S16P + uo] = s8;
    }
    asm volatile("s_waitcnt lgkmcnt(0)" ::: "memory");
    __builtin_amdgcn_s_barrier();
    __builtin_amdgcn_sched_barrier(0);

    // ---- phase B: op1 (deps for t+1 | store h[t-1]) ----
    if (w < 3) {
      int tn = (t + 1 < T_N) ? (t + 1) : (T_N - 1);
      int d0v = sidx_all[r0][tn][4 + dm0];
      glds16(dsrc0 + (size_t)d0v * (B_N * 256), &dbuf[(t + 1) & 1][(4 * w) * 256]);
      int d1v = sidx_all[r1][tn][4 + dm1];
      glds16(dsrc1 + (size_t)d1v * (B_N * 256), &dbuf[(t + 1) & 1][(4 * w + 2) * 256]);
    } else {
      int tt = (t == 0) ? T_N : (t - 1);
      f16x8 hv0 = *(const f16x8*)&hring[(t + 1) & 1][srow0 * 256 + soff];
      *(f16x8*)(H16 + ((size_t)tt * B_N + b0 + srow0) * 256 + soff) = hv0;
      f16x8 hv1 = *(const f16x8*)&hring[(t + 1) & 1][srow1 * 256 + soff];
      *(f16x8*)(H16 + ((size_t)tt * B_N + b0 + srow1) * 256 + soff) = hv1;
    }
    __builtin_amdgcn_sched_barrier(0);
    // op2: pre row t+2 (2 ops)
    {
      int t2 = (t + 2 < T_N) ? (t + 2) : (T_N - 1);
      glds16(spre_src + (size_t)t2 * 1024,       &spre[(t + 2) % 3][sprd]);
      glds16(spre_src + (size_t)t2 * 1024 + 512, &spre[(t + 2) % 3][sprd + 512]);
    }
    __builtin_amdgcn_sched_barrier(0);

    // ---- MFMA: msg = s @ Uh (wave's 192-col slice), builtin (hazards handled) ----
    f32x4 acc[12];
    #pragma unroll
    for (int i = 0; i < 12; ++i) acc[i] = (f32x4){0.f, 0.f, 0.f, 0.f};
    __builtin_amdgcn_s_setprio(1);
    #pragma unroll
    for (int kk = 0; kk < 8; ++kk) {
      f16x8 a = *(const f16x8*)(s16 + l15 * S16P + kk * 32 + lhi * 8);
      #pragma unroll
      for (int nt = 0; nt < 12; ++nt)
        acc[nt] = __builtin_amdgcn_mfma_f32_16x16x32_f16(a, uh[kk * 12 + nt], acc[nt], 0, 0, 0);
    }
    __builtin_amdgcn_s_setprio(0);

    // ---- update: thread (w,lhi,l15) -> batch row lhi, u = w*64 + ub*16 + l15 ----
    {
      const int* six = &sidx_all[lhi][t][0];
      int c0 = six[0], c1 = six[1], c2 = six[2], c3 = six[3];
      int mfl = six[7];
      float cnt  = (float)(c0 + c1 + c2 + c3);
      float rcnt = __builtin_amdgcn_rcpf(fmaxf(cnt, 1.f));
      #pragma unroll
      for (int ub = 0; ub < 4; ++ub) {
        int u = w * 64 + ub * 16 + l15;
        f16x4 p = *(const f16x4*)&spre[t % 3][lhi * 1024 + u * 4];
        float mr = acc[3 * ub + 0][0];
        float mz = acc[3 * ub + 1][0];
        float mh = acc[3 * ub + 2][0];
        float tr = (float)p.x + mr;
        float tz = (float)p.y + mz;
        float hx = (float)p.z;
        float he = (float)p.w;
        float rg = __builtin_amdgcn_rcpf(1.f + __expf(-tr));
        float zg = __builtin_amdgcn_rcpf(1.f + __expf(-tz));
        float aa = hx + rg * (mh + he);
        float hc = 2.f * __builtin_amdgcn_rcpf(1.f + __expf(-2.f * aa)) - 1.f;
        float sv = (float)s16[(lhi * 4) * S16P + u];
        float hb = sv * rcnt;
        float hn = zg * hb + (1.f - zg) * hc;
        float hp_ = (float)hring[(t + 1) & 1][lhi * 256 + u];
        float ho = mfl ? hn : hp_;
        hring[t & 1][lhi * 256 + u] = (f16)ho;
      }
    }
    asm volatile("s_waitcnt lgkmcnt(0)" ::: "memory");
    __builtin_amdgcn_s_barrier();
    __builtin_amdgcn_sched_barrier(0);
  }

  // ---- epilogue: out = m[T-1] ? h[T-1] : 0 ----
  if (tid < 128) {
    const int rr = tid >> 5, uo = (tid & 31) * 8;
    int m = sidx_all[rr][T_N - 1][7];
    f16x8 h8 = *(const f16x8*)&hring[(T_N - 1) & 1][rr * 256 + uo];
    f32x4 o0, o1;
    #pragma unroll
    for (int j = 0; j < 4; ++j) {
      o0[j] = m ? (float)h8[j]     : 0.f;
      o1[j] = m ? (float)h8[j + 4] : 0.f;
    }
    *(f32x4*)(out + (size_t)(b0 + rr) * 256 + uo)     = o0;
    *(f32x4*)(out + (size_t)(b0 + rr) * 256 + uo + 4) = o1;
  }
}

extern "C" void kernel_launch(void* const* d_in, const int* in_sizes, int n_in,
                              void* d_out, int out_size, void* d_ws, size_t ws_size,
                              hipStream_t stream)
{
  const float* inputs = (const float*)d_in[0];
  const int*   deps   = (const int*)d_in[2];
  const int*   et     = (const int*)d_in[3];
  const int*   msk    = (const int*)d_in[4];
  const int*   cmk    = (const int*)d_in[5];
  const float* Wx     = (const float*)d_in[6];
  const float* Uh     = (const float*)d_in[7];
  const float* Ve     = (const float*)d_in[8];
  const float* bb     = (const float*)d_in[9];
  const float* emb    = (const float*)d_in[10];
  float* out = (float*)d_out;

  char* ws = (char*)d_ws;
  f16*   A2    = (f16*)ws;                     // 128 MB (dead after GEMM)
  f16*   H16   = (f16*)ws;                     // 66 MB alias of A2 (T+1 rows)
  f16*   pre   = (f16*)(ws + 134217728);       // 256 MB
  f16*   B2    = (f16*)(ws + 402653184);       // 1 MB
  float* bias  = (float*)(ws + 403701760);     // 4 KB
  f16*   UhF   = (f16*)(ws + 403705856);       // 384 KB

  int prep_n = NC * KC + U_N * G3 + NC;
  k_prep<<<dim3((prep_n + 255) / 256), dim3(256), 0, stream>>>(Wx, Uh, Ve, bb, B2, bias, UhF);
  k_build_a2<<<dim3(M_N * 64 / 256), dim3(256), 0, stream>>>(inputs, et, cmk, emb, A2);
  k_gemm2<<<dim3((M_N / 128) * (NC / 128)), dim3(256), 0, stream>>>(A2, B2, bias, pre);
  k_scan7<<<dim3(B_N / 4), dim3(256), 0, stream>>>(pre, UhF, deps, cmk, msk, H16, out);
}

// Round 11
// 506.068 us; speedup vs baseline: 1.2061x; 1.2061x over previous
//
#include <hip/hip_runtime.h>
#include <hip/hip_bf16.h>
#include <stdint.h>

typedef _Float16 f16;
typedef _Float16 f16x8 __attribute__((ext_vector_type(8)));
typedef _Float16 f16x4 __attribute__((ext_vector_type(4)));
typedef float    f32x4 __attribute__((ext_vector_type(4)));

#define B_N 1024
#define T_N 128
#define U_N 256
#define G3  768    // 3U
#define NC  1024   // pre columns, permuted: col' = u*4 + part, part in {r,z,xh,eh}
#define KC  512    // concat K: [inputs | em_sum]
#define M_N (B_N * T_N)
#define S16P 264   // f16 LDS row stride

__device__ __forceinline__ void glds16(const void* g, void* l) {
  __builtin_amdgcn_global_load_lds((const __attribute__((address_space(1))) unsigned int*)g,
                                   (__attribute__((address_space(3))) unsigned int*)l, 16, 0, 0);
}
__device__ __forceinline__ void glds4(const void* g, void* l) {
  __builtin_amdgcn_global_load_lds((const __attribute__((address_space(1))) unsigned int*)g,
                                   (__attribute__((address_space(3))) unsigned int*)l, 4, 0, 0);
}

// ---------------- prep: B2 (f16, tile-major pre-swizzled), bias' (f32 1024), UhF (8-wave layout) ----------------
__global__ void k_prep(const float* __restrict__ Wx, const float* __restrict__ Uh,
                       const float* __restrict__ Ve, const float* __restrict__ bsrc,
                       f16* __restrict__ B2, float* __restrict__ bias, f16* __restrict__ UhF)
{
  int idx = blockIdx.x * 256 + threadIdx.x;
  if (idx < NC * KC) {
    int e = idx & 7, slot = (idx >> 3) & 3, r = (idx >> 5) & 127;
    int kt = (idx >> 12) & 15, nt8 = idx >> 16;
    int swz = ((r >> 2) ^ r) & 3;
    int np = nt8 * 128 + r;
    int k  = kt * 32 + ((slot ^ swz) & 3) * 8 + e;
    int u = np >> 2, part = np & 3;
    float v;
    if (part == 0)      v = (k < 256) ? Wx[k * G3 + u]         : Ve[(k - 256) * G3 + u];
    else if (part == 1) v = (k < 256) ? Wx[k * G3 + 256 + u]   : Ve[(k - 256) * G3 + 256 + u];
    else if (part == 2) v = (k < 256) ? Wx[k * G3 + 512 + u]   : 0.f;
    else                v = (k < 256) ? 0.f                    : Ve[(k - 256) * G3 + 512 + u];
    B2[idx] = (f16)v;
    return;
  }
  int i2 = idx - NC * KC;
  if (i2 < U_N * G3) {
    int j = i2 & 7, lane = (i2 >> 3) & 63, fn = i2 >> 9;   // fn = (w*8+kk)*6+nt
    int nt = fn % 6, kkw = fn / 6;
    int kk = kkw & 7, w = kkw >> 3;
    int k = kk * 32 + (lane >> 4) * 8 + j;
    int npp = w * 96 + nt * 16 + (lane & 15);
    int q = npp >> 4;
    int u = (q / 3) * 16 + (npp & 15), gate = q % 3;
    UhF[i2] = (f16)Uh[k * G3 + gate * 256 + u];
    return;
  }
  int i3 = i2 - U_N * G3;
  if (i3 < NC) {
    int u = i3 >> 2, part = i3 & 3;
    bias[i3] = (part < 3) ? bsrc[part * 256 + u] : 0.f;
  }
}

// ---------------- build A2 (f16, tile-major pre-swizzled) ----------------
__global__ __launch_bounds__(256) void k_build_a2(const float* __restrict__ inp, const int* __restrict__ et,
                           const int* __restrict__ cmk, const float* __restrict__ emb,
                           f16* __restrict__ A2)
{
  int idx = blockIdx.x * 256 + threadIdx.x;        // 8,388,608 total
  int slot = idx & 3, t = (idx >> 2) & 127, kt = (idx >> 9) & 15, b = idx >> 13;
  int swz = ((t >> 2) ^ t) & 3;
  int k0 = kt * 32 + ((slot ^ swz) & 3) * 8;
  int m = b * 128 + t;
  f16x8 v;
  if (k0 < 256) {
    const float* s = inp + (size_t)m * 256 + k0;
    #pragma unroll
    for (int j = 0; j < 8; ++j) v[j] = (f16)s[j];
  } else {
    int c = k0 - 256;
    const int* e  = et  + (size_t)m * 4;
    const int* cm = cmk + (size_t)m * 4;
    float a[8] = {0,0,0,0,0,0,0,0};
    #pragma unroll
    for (int r = 0; r < 4; ++r)
      if (cm[r]) {
        const float* es = emb + e[r] * U_N + c;
        #pragma unroll
        for (int j = 0; j < 8; ++j) a[j] += es[j];
      }
    #pragma unroll
    for (int j = 0; j < 8; ++j) v[j] = (f16)a[j];
  }
  *(f16x8*)(A2 + (size_t)idx * 8) = v;
}

// ---------------- GEMM: pre[M][1024] (f16) = A[M][512] @ B^T + bias' (R6-proven) ----------------
__global__ __launch_bounds__(256) void k_gemm2(const f16* __restrict__ A2,
                                               const f16* __restrict__ B2,
                                               const float* __restrict__ bias,
                                               f16* __restrict__ C)
{
  __shared__ __align__(16) f16 sbuf[3][2][4096];   // 49152 B
  const int tid  = threadIdx.x;
  const int lane = tid & 63, wv = tid >> 6;
  const int wm = wv >> 1, wn = wv & 1;
  const int l15 = lane & 15, lhi = lane >> 4;
  const int wg = (blockIdx.x & 7) * 1024 + (blockIdx.x >> 3);
  const int mt = wg >> 3, nt = wg & 7;
  const int m0 = mt * 128, n0 = nt * 128;

  const f16* gabase = A2 + (size_t)mt * 16 * 4096 + wv * 1024 + lane * 8;
  const f16* gbbase = B2 + (size_t)nt * 16 * 4096 + wv * 1024 + lane * 8;

  #define STAGE(kt_, buf_) do {                                             \
    int kk_ = (kt_);                                                        \
    glds16(gabase + (size_t)kk_ * 4096,       &sbuf[buf_][0][wv * 1024]);   \
    glds16(gabase + (size_t)kk_ * 4096 + 512, &sbuf[buf_][0][wv * 1024 + 512]); \
    glds16(gbbase + (size_t)kk_ * 4096,       &sbuf[buf_][1][wv * 1024]);   \
    glds16(gbbase + (size_t)kk_ * 4096 + 512, &sbuf[buf_][1][wv * 1024 + 512]); \
  } while (0)

  f32x4 acc[4][4] = {};

  STAGE(0, 0);
  STAGE(1, 1);
  __builtin_amdgcn_sched_barrier(0);

  int aoff[4], boff[4];
  #pragma unroll
  for (int i = 0; i < 4; ++i) {
    int ar = wm * 64 + i * 16 + l15;
    aoff[i] = ar * 32 + ((lhi ^ ((ar >> 2) ^ ar)) & 3) * 8;
    int br = wn * 64 + i * 16 + l15;
    boff[i] = br * 32 + ((lhi ^ ((br >> 2) ^ br)) & 3) * 8;
  }

  for (int t = 0; t < 16; ++t) {
    const int buf  = t % 3;
    const int bufp = (t + 2) % 3;
    STAGE((t + 2 < 16) ? (t + 2) : 15, bufp);
    __builtin_amdgcn_sched_barrier(0);
    asm volatile("s_waitcnt vmcnt(8)" ::: "memory");
    __builtin_amdgcn_sched_barrier(0);
    __builtin_amdgcn_s_barrier();
    __builtin_amdgcn_sched_barrier(0);

    const f16* sA = &sbuf[buf][0][0];
    const f16* sB = &sbuf[buf][1][0];
    f16x8 af[4], bf[4];
    #pragma unroll
    for (int i = 0; i < 4; ++i) {
      af[i] = *(const f16x8*)(sA + aoff[i]);
      bf[i] = *(const f16x8*)(sB + boff[i]);
    }
    __builtin_amdgcn_s_setprio(1);
    #pragma unroll
    for (int i = 0; i < 4; ++i)
      #pragma unroll
      for (int j = 0; j < 4; ++j)
        acc[i][j] = __builtin_amdgcn_mfma_f32_16x16x32_f16(af[i], bf[j], acc[i][j], 0, 0, 0);
    __builtin_amdgcn_s_setprio(0);

    asm volatile("s_waitcnt lgkmcnt(0)" ::: "memory");
    __builtin_amdgcn_s_barrier();
    __builtin_amdgcn_sched_barrier(0);
  }

  float bv[4];
  #pragma unroll
  for (int j = 0; j < 4; ++j) bv[j] = bias[n0 + wn * 64 + j * 16 + l15];
  asm volatile("s_waitcnt vmcnt(0)" ::: "memory");
  __builtin_amdgcn_sched_barrier(0);
  __builtin_amdgcn_s_barrier();

  f16* ep = &sbuf[0][0][0];
  #pragma unroll
  for (int i = 0; i < 4; ++i)
    #pragma unroll
    for (int j = 0; j < 4; ++j)
      #pragma unroll
      for (int r = 0; r < 4; ++r)
        ep[(wm * 64 + i * 16 + lhi * 4 + r) * 132 + wn * 64 + j * 16 + l15] =
            (f16)(acc[i][j][r] + bv[j]);
  __syncthreads();

  #pragma unroll
  for (int it = 0; it < 8; ++it) {
    int row = it * 16 + (tid >> 4), chunk = tid & 15;
    *(f16x8*)(C + (size_t)(m0 + row) * 1024 + n0 + chunk * 8) =
        *(const f16x8*)(ep + row * 132 + chunk * 8);
  }
  #undef STAGE
}

// ---------------- scan: 256 blocks x 512 threads, 4 batch rows per block (R6-proven base) ----------------
// Change vs R6: 32 of 48 Uh fragments pinned in registers via opaque asm (non-rematerializable),
// cutting per-step L2 Uh re-fetch traffic 3x. Remaining 16 frags keep compiler reload path.
__global__ __launch_bounds__(512, 2) void k_scan4(
    const f16* __restrict__ pre,   // [B*T][1024], col' = u*4 + {r,z,xh,eh}
    const f16* __restrict__ UhF,
    const int* __restrict__ dep,   // [B][T][3]
    const int* __restrict__ cmk,   // [B][T][4]
    const int* __restrict__ msk,   // [B][T]
    f16* __restrict__ H16,         // [T+1][B][256] f16 (row T = scratch)
    float* __restrict__ out)       // [B][256]
{
  __shared__ __align__(16) f16 s16[16 * S16P];
  __shared__ __align__(16) f16 hring[2][1024];
  __shared__ __align__(16) f16 dbuf[2][3072];
  __shared__ __align__(16) f16 spre[3][4096];
  __shared__ __align__(16) int sidxl[4][64];
  __shared__ __align__(16) int dpad[64];

  const int tid  = threadIdx.x;
  const int lane = tid & 63, w = tid >> 6;
  const int l15  = lane & 15, lhi = lane >> 4;
  const int b0   = blockIdx.x * 4;

  // Uh fragments; first 32 pinned resident (opaque), last 16 rematerializable (L2 stream)
  f16x8 uh[48];
  {
    const f16* ub = UhF + ((size_t)w * 48 * 64 + lane) * 8;
    #pragma unroll
    for (int i = 0; i < 48; ++i) uh[i] = *(const f16x8*)(ub + i * 512);
    #pragma unroll
    for (int i = 0; i < 32; ++i) asm volatile("" : "+v"(uh[i]));
  }

  ((int*)hring)[tid]       = 0;
  ((int*)hring)[tid + 512] = 0;

  if (tid < 96) {
    int tt = tid >> 5, ll2 = tid & 31, rr = ll2 >> 3, f = ll2 & 7;
    size_t b = b0 + rr;
    int v;
    if (f < 4)      v = cmk[(b * T_N + tt) * 4 + f];
    else if (f < 7) v = dep[(b * T_N + tt) * 3 + (f - 4)];
    else            v = msk[b * T_N + tt];
    sidxl[tt][rr * 8 + f] = v;
  }
  __syncthreads();

  const f16* spre_src = pre + ((size_t)(b0 + (w >> 1)) * T_N) * 1024 + (w & 1) * 512 + lane * 8;
  const int  ll = lane & 31;
  const int  srr = ll >> 3, sf = ll & 7;
  const size_t sb = b0 + srr;
  const int* sidx_base;
  int sidx_stride;
  if (sf < 4)      { sidx_base = cmk + sb * T_N * 4 + sf;       sidx_stride = 4; }
  else if (sf < 7) { sidx_base = dep + sb * T_N * 3 + (sf - 4); sidx_stride = 3; }
  else             { sidx_base = msk + sb * T_N;                sidx_stride = 1; }
  const int dq  = 2 * w + (lane >> 5);
  const int drr = dq / 3, drm = dq - drr * 3;
  const f16* dsrc_base = H16 + (size_t)(b0 + drr) * 256 + (lane & 31) * 8;
  const int strr = ((w - 6) * 64 + lane) >> 5;
  const int stuo = (((w - 6) * 64 + lane) & 31) * 8;

  #pragma unroll
  for (int pr = 0; pr < 2; ++pr)
    glds16(spre_src + (size_t)pr * 1024, &spre[pr][w * 512]);
  #pragma unroll
  for (int i = 0; i < 3; ++i)
    glds4(msk, &dpad[0]);

  for (int t = 0; t < T_N; ++t) {
    asm volatile("s_waitcnt vmcnt(2)" ::: "memory");
    __builtin_amdgcn_sched_barrier(0);

    if (tid < 128) {
      const int rr = tid >> 5, uo = (tid & 31) * 8;
      const int* six = &sidxl[t & 3][rr * 8];
      int cm0 = six[0];
      int cms0 = six[1], cms1 = six[2], cms2 = six[3];
      int dd0 = six[4],  dd1 = six[5],  dd2 = six[6];
      f16x8 hprev = *(const f16x8*)&hring[(t + 1) & 1][rr * 256 + uo];
      f16x8 hold  = *(const f16x8*)&hring[t & 1][rr * 256 + uo];
      f32x4 a0 = {0.f,0.f,0.f,0.f}, a1 = {0.f,0.f,0.f,0.f};
      if (cm0) {
        #pragma unroll
        for (int j = 0; j < 4; ++j) { a0[j] += (float)hprev[j]; a1[j] += (float)hprev[j + 4]; }
      }
      int cma[3] = {cms0, cms1, cms2};
      int dda[3] = {dd0, dd1, dd2};
      #pragma unroll
      for (int r = 0; r < 3; ++r) {
        f16x8 dv = *(const f16x8*)&dbuf[t & 1][(rr * 3 + r) * 256 + uo];
        int d = dda[r];
        f16x8 src = (d == t - 1) ? hprev : ((d == t - 2) ? hold : dv);
        if (cma[r] && (d < t)) {
          #pragma unroll
          for (int j = 0; j < 4; ++j) { a0[j] += (float)src[j]; a1[j] += (float)src[j + 4]; }
        }
      }
      f16x8 s8;
      #pragma unroll
      for (int j = 0; j < 4; ++j) { s8[j] = (f16)a0[j]; s8[j + 4] = (f16)a1[j]; }
      *(f16x8*)&s16[(rr * 4) * S16P + uo] = s8;
    }
    asm volatile("s_waitcnt lgkmcnt(0)" ::: "memory");
    __builtin_amdgcn_s_barrier();
    __builtin_amdgcn_sched_barrier(0);

    if (w < 6) {
      int d = sidxl[(t + 1) & 3][drr * 8 + 4 + drm];
      glds16(dsrc_base + (size_t)d * (B_N * 256), &dbuf[(t + 1) & 1][w * 512]);
    } else {
      f16x8 hv = *(const f16x8*)&hring[(t + 1) & 1][strr * 256 + stuo];
      int tt = (t == 0) ? T_N : (t - 1);
      *(f16x8*)(H16 + ((size_t)tt * B_N + b0 + strr) * 256 + stuo) = hv;
    }
    __builtin_amdgcn_sched_barrier(0);
    {
      int tt2 = (t + 2 < T_N) ? (t + 2) : (T_N - 1);
      glds16(spre_src + (size_t)tt2 * 1024, &spre[(t + 2) % 3][w * 512]);
    }
    __builtin_amdgcn_sched_barrier(0);
    {
      int t3 = (t + 3 < T_N) ? (t + 3) : (T_N - 1);
      glds4(sidx_base + (size_t)t3 * sidx_stride, &sidxl[(t + 3) & 3][0]);
    }
    __builtin_amdgcn_sched_barrier(0);

    f32x4 acc[6];
    #pragma unroll
    for (int i = 0; i < 6; ++i) acc[i] = (f32x4){0.f, 0.f, 0.f, 0.f};
    __builtin_amdgcn_s_setprio(1);
    #pragma unroll
    for (int kk = 0; kk < 8; ++kk) {
      f16x8 a = *(const f16x8*)(s16 + l15 * S16P + kk * 32 + lhi * 8);
      #pragma unroll
      for (int nt = 0; nt < 6; ++nt)
        acc[nt] = __builtin_amdgcn_mfma_f32_16x16x32_f16(a, uh[kk * 6 + nt], acc[nt], 0, 0, 0);
    }
    __builtin_amdgcn_s_setprio(0);

    asm volatile("s_waitcnt vmcnt(7)" ::: "memory");
    __builtin_amdgcn_sched_barrier(0);
    {
      const int* six = &sidxl[t & 3][lhi * 8];
      int c0 = six[0], c1 = six[1], c2 = six[2], c3 = six[3];
      int mfl = six[7];
      float cnt  = (float)(c0 + c1 + c2 + c3);
      float rcnt = __builtin_amdgcn_rcpf(fmaxf(cnt, 1.f));
      #pragma unroll
      for (int ub2 = 0; ub2 < 2; ++ub2) {
        int u = w * 32 + ub2 * 16 + l15;
        f16x4 p = *(const f16x4*)&spre[t % 3][lhi * 1024 + u * 4];
        float mr = acc[ub2 * 3 + 0][0];
        float mz = acc[ub2 * 3 + 1][0];
        float mh = acc[ub2 * 3 + 2][0];
        float tr = (float)p.x + mr;
        float tz = (float)p.y + mz;
        float hx = (float)p.z;
        float he = (float)p.w;
        float rg = __builtin_amdgcn_rcpf(1.f + __expf(-tr));
        float zg = __builtin_amdgcn_rcpf(1.f + __expf(-tz));
        float aa = hx + rg * (mh + he);
        float hc = 2.f * __builtin_amdgcn_rcpf(1.f + __expf(-2.f * aa)) - 1.f;
        float sv = (float)s16[(lhi * 4) * S16P + u];
        float hb = sv * rcnt;
        float hn = zg * hb + (1.f - zg) * hc;
        float hp_ = (float)hring[(t + 1) & 1][lhi * 256 + u];
        float ho = mfl ? hn : hp_;
        hring[t & 1][lhi * 256 + u] = (f16)ho;
      }
    }
    asm volatile("s_waitcnt lgkmcnt(0)" ::: "memory");
    __builtin_amdgcn_s_barrier();
    __builtin_amdgcn_sched_barrier(0);
  }

  if (tid < 128) {
    const int rr = tid >> 5, uo = (tid & 31) * 8;
    int m = sidxl[(T_N - 1) & 3][rr * 8 + 7];
    f16x8 h8 = *(const f16x8*)&hring[(T_N - 1) & 1][rr * 256 + uo];
    f32x4 o0, o1;
    #pragma unroll
    for (int j = 0; j < 4; ++j) {
      o0[j] = m ? (float)h8[j]     : 0.f;
      o1[j] = m ? (float)h8[j + 4] : 0.f;
    }
    *(f32x4*)(out + (size_t)(b0 + rr) * 256 + uo)     = o0;
    *(f32x4*)(out + (size_t)(b0 + rr) * 256 + uo + 4) = o1;
  }
}

extern "C" void kernel_launch(void* const* d_in, const int* in_sizes, int n_in,
                              void* d_out, int out_size, void* d_ws, size_t ws_size,
                              hipStream_t stream)
{
  const float* inputs = (const float*)d_in[0];
  const int*   deps   = (const int*)d_in[2];
  const int*   et     = (const int*)d_in[3];
  const int*   msk    = (const int*)d_in[4];
  const int*   cmk    = (const int*)d_in[5];
  const float* Wx     = (const float*)d_in[6];
  const float* Uh     = (const float*)d_in[7];
  const float* Ve     = (const float*)d_in[8];
  const float* bb     = (const float*)d_in[9];
  const float* emb    = (const float*)d_in[10];
  float* out = (float*)d_out;

  char* ws = (char*)d_ws;
  f16*   A2    = (f16*)ws;                     // 128 MB (dead after GEMM)
  f16*   H16   = (f16*)ws;                     // 66 MB alias of A2 (T+1 rows)
  f16*   pre   = (f16*)(ws + 134217728);       // 256 MB
  f16*   B2    = (f16*)(ws + 402653184);       // 1 MB
  float* bias  = (float*)(ws + 403701760);     // 4 KB
  f16*   UhF   = (f16*)(ws + 403705856);       // 384 KB

  int prep_n = NC * KC + U_N * G3 + NC;
  k_prep<<<dim3((prep_n + 255) / 256), dim3(256), 0, stream>>>(Wx, Uh, Ve, bb, B2, bias, UhF);
  k_build_a2<<<dim3(M_N * 64 / 256), dim3(256), 0, stream>>>(inputs, et, cmk, emb, A2);
  k_gemm2<<<dim3((M_N / 128) * (NC / 128)), dim3(256), 0, stream>>>(A2, B2, bias, pre);
  k_scan4<<<dim3(B_N / 4), dim3(512), 0, stream>>>(pre, UhF, deps, cmk, msk, H16, out);
}